// Round 1
// baseline (528.140 us; speedup 1.0000x reference)
//
#include <hip/hip_runtime.h>
#include <hip/hip_bf16.h>
#include <math.h>

// Problem constants (BahdanauAttention): B=32, T=2048, D=512, U=512, fp32.
#define BB 32
#define TT 2048
#define DD 512
#define UU 512

// ---------------------------------------------------------------------------
// K1: qb[b,u] = query[b,:] @ W2[:,u] + b2[u] + b1[u]   (fold b1 in here)
// grid (B, U/256), block 256
// ---------------------------------------------------------------------------
__global__ __launch_bounds__(256) void projq_kernel(
    const float* __restrict__ query, const float* __restrict__ W2,
    const float* __restrict__ b2, const float* __restrict__ b1,
    float* __restrict__ qb) {
  int b = blockIdx.x;
  int u = blockIdx.y * 256 + threadIdx.x;
  float acc = b2[u] + b1[u];
  const float* q = query + b * DD;
  #pragma unroll 8
  for (int d = 0; d < DD; ++d) {
    acc += q[d] * W2[(size_t)d * UU + u];  // coalesced across u
  }
  qb[b * UU + u] = acc;
}

// ---------------------------------------------------------------------------
// K2: fused GEMM + tanh + V-reduction.
// score[row] += sum_{u in ntile} tanh( values[row,:]@W1[:,u] + qb[b,u] ) * V[u]
// M = B*T = 65536 rows; tiles: BM=64, BN=64, BK=16; 256 threads, 4x4/thread.
// grid (U/BN=8, M/BM=1024)
// ---------------------------------------------------------------------------
#define BM 64
#define BN 64
#define BK 16

__global__ __launch_bounds__(256) void score_kernel(
    const float* __restrict__ values, const float* __restrict__ W1,
    const float* __restrict__ qb, const float* __restrict__ V,
    float* __restrict__ score) {
  __shared__ float As[BK][BM];  // transposed A tile: As[k][m]
  __shared__ float Bs[BK][BN];

  const int tid = threadIdx.x;
  const int tx = tid & 15;        // 0..15 -> n
  const int ty = tid >> 4;        // 0..15 -> m
  const int n0 = blockIdx.x * BN;
  const int row0 = blockIdx.y * BM;
  const int b = row0 / TT;        // BM divides T, so one batch per row-tile

  // global->LDS load indices
  const int lm = tid >> 2;              // 0..63 row in A tile
  const int lk = (tid & 3) * 4;         // 0,4,8,12 k in A tile
  const int bk = tid >> 4;              // 0..15 k in B tile
  const int bn = (tid & 15) * 4;        // n in B tile

  float acc[4][4] = {};

  for (int k0 = 0; k0 < DD; k0 += BK) {
    // stage A (values) tile, transposed into As[k][m]
    const float4 av = *(const float4*)(values + (size_t)(row0 + lm) * DD + k0 + lk);
    As[lk + 0][lm] = av.x;
    As[lk + 1][lm] = av.y;
    As[lk + 2][lm] = av.z;
    As[lk + 3][lm] = av.w;
    // stage B (W1) tile
    *(float4*)&Bs[bk][bn] = *(const float4*)(W1 + (size_t)(k0 + bk) * UU + n0 + bn);
    __syncthreads();

    #pragma unroll
    for (int k = 0; k < BK; ++k) {
      const float4 a = *(const float4*)&As[k][ty * 4];
      const float4 w = *(const float4*)&Bs[k][tx * 4];
      const float ar[4] = {a.x, a.y, a.z, a.w};
      const float wr[4] = {w.x, w.y, w.z, w.w};
      #pragma unroll
      for (int i = 0; i < 4; ++i)
        #pragma unroll
        for (int j = 0; j < 4; ++j)
          acc[i][j] += ar[i] * wr[j];
    }
    __syncthreads();
  }

  // epilogue: tanh + multiply by V, reduce over this block's 64 u's per row
  #pragma unroll
  for (int i = 0; i < 4; ++i) {
    float part = 0.f;
    #pragma unroll
    for (int j = 0; j < 4; ++j) {
      const int u = n0 + tx * 4 + j;
      part += tanhf(acc[i][j] + qb[b * UU + u]) * V[u];
    }
    // reduce across the 16 tx lanes (same ty -> 16 consecutive lanes in a wave)
    #pragma unroll
    for (int off = 1; off < 16; off <<= 1)
      part += __shfl_xor(part, off, 64);
    if (tx == 0) atomicAdd(&score[row0 + ty * 4 + i], part);
  }
}

// ---------------------------------------------------------------------------
// K3: softmax over T per batch. grid (B), block 256.
// ---------------------------------------------------------------------------
__global__ __launch_bounds__(256) void softmax_kernel(
    const float* __restrict__ score, float* __restrict__ attn) {
  const int b = blockIdx.x;
  const int tid = threadIdx.x;
  __shared__ float red[256];

  // pass 1: max
  float m = -INFINITY;
  for (int t = tid; t < TT; t += 256) m = fmaxf(m, score[b * TT + t]);
  red[tid] = m;
  __syncthreads();
  for (int s = 128; s > 0; s >>= 1) {
    if (tid < s) red[tid] = fmaxf(red[tid], red[tid + s]);
    __syncthreads();
  }
  const float bm = red[0];
  __syncthreads();

  // pass 2: sum of exp
  float sum = 0.f;
  for (int t = tid; t < TT; t += 256) sum += __expf(score[b * TT + t] - bm);
  red[tid] = sum;
  __syncthreads();
  for (int s = 128; s > 0; s >>= 1) {
    if (tid < s) red[tid] += red[tid + s];
    __syncthreads();
  }
  const float inv = 1.f / red[0];
  __syncthreads();

  // pass 3: write weights
  for (int t = tid; t < TT; t += 256)
    attn[b * TT + t] = __expf(score[b * TT + t] - bm) * inv;
}

// ---------------------------------------------------------------------------
// K4: context[b,d] = sum_t attn[b,t] * values[b,t,d]
// grid (SPLIT=16, B), block 256; each thread owns 2 d's; atomicAdd partials.
// ---------------------------------------------------------------------------
#define SPLIT 16
__global__ __launch_bounds__(256) void context_kernel(
    const float* __restrict__ values, const float* __restrict__ attn,
    float* __restrict__ ctx) {
  const int b = blockIdx.y;
  const int t0 = blockIdx.x * (TT / SPLIT);
  const int d0 = threadIdx.x;
  const int d1 = threadIdx.x + 256;
  float a0 = 0.f, a1 = 0.f;
  for (int t = t0; t < t0 + TT / SPLIT; ++t) {
    const float w = attn[b * TT + t];
    const float* vrow = values + (size_t)(b * TT + t) * DD;
    a0 += w * vrow[d0];
    a1 += w * vrow[d1];
  }
  atomicAdd(&ctx[b * DD + d0], a0);
  atomicAdd(&ctx[b * DD + d1], a1);
}

// ---------------------------------------------------------------------------
extern "C" void kernel_launch(void* const* d_in, const int* in_sizes, int n_in,
                              void* d_out, int out_size, void* d_ws, size_t ws_size,
                              hipStream_t stream) {
  const float* query  = (const float*)d_in[0];
  const float* values = (const float*)d_in[1];
  const float* W1     = (const float*)d_in[2];
  const float* b1     = (const float*)d_in[3];
  const float* W2     = (const float*)d_in[4];
  const float* b2     = (const float*)d_in[5];
  const float* V      = (const float*)d_in[6];
  // d_in[7] = bV: uniform score shift -> softmax-invariant, dropped.

  float* ctx  = (float*)d_out;             // [B,D]   = 16384 floats
  float* attn = (float*)d_out + BB * DD;   // [B,T,1] = 65536 floats

  float* qb    = (float*)d_ws;             // [B,U]
  float* score = qb + BB * UU;             // [B*T]

  // zero accumulation buffers (graph-capture-safe stream ops)
  hipMemsetAsync(ctx, 0, BB * DD * sizeof(float), stream);
  hipMemsetAsync(score, 0, (size_t)BB * TT * sizeof(float), stream);

  projq_kernel<<<dim3(BB, UU / 256), 256, 0, stream>>>(query, W2, b2, b1, qb);

  score_kernel<<<dim3(UU / BN, (BB * TT) / BM), 256, 0, stream>>>(
      values, W1, qb, V, score);

  softmax_kernel<<<BB, 256, 0, stream>>>(score, attn);

  context_kernel<<<dim3(SPLIT, BB), 256, 0, stream>>>(values, attn, ctx);
}

// Round 2
// 157.840 us; speedup vs baseline: 3.3460x; 3.3460x over previous
//
#include <hip/hip_runtime.h>
#include <hip/hip_bf16.h>
#include <math.h>

// BahdanauAttention: B=32, T=2048, D=512, U=512, fp32 in/out.
#define BB 32
#define TT 2048
#define DD 512
#define UU 512

typedef __attribute__((ext_vector_type(8))) short short8v;     // MFMA bf16 A/B frag (8 bf16)
typedef __attribute__((ext_vector_type(4))) float floatx4;     // MFMA C/D frag
typedef __attribute__((ext_vector_type(8))) unsigned short ushort8v;

static __device__ inline unsigned short f2bf(float f) {
  __hip_bfloat16 h = __float2bfloat16(f);
  return *reinterpret_cast<unsigned short*>(&h);
}

static __device__ inline float fast_tanh(float x) {
  x = fminf(fmaxf(x, -15.f), 15.f);
  float e2 = __expf(2.f * x);
  return (e2 - 1.f) * __builtin_amdgcn_rcpf(e2 + 1.f);
}

// ---------------------------------------------------------------------------
// K0: transpose W1[k][n] fp32 -> W1t[n][k] bf16 (so GEMM B-tile is k-minor)
// grid (16,16), block (32,8)
// ---------------------------------------------------------------------------
__global__ __launch_bounds__(256) void transpose_w1_kernel(
    const float* __restrict__ W1, unsigned short* __restrict__ W1t) {
  __shared__ float tile[32][33];
  const int tx = threadIdx.x, ty = threadIdx.y;
  const int bk = blockIdx.y * 32, bn = blockIdx.x * 32;
  #pragma unroll
  for (int i = 0; i < 4; ++i)
    tile[ty + i * 8][tx] = W1[(size_t)(bk + ty + i * 8) * UU + bn + tx];
  __syncthreads();
  #pragma unroll
  for (int i = 0; i < 4; ++i)
    W1t[(size_t)(bn + ty + i * 8) * DD + bk + tx] = f2bf(tile[tx][ty + i * 8]);
}

// ---------------------------------------------------------------------------
// K1: qb[b,u] = query[b,:] @ W2[:,u] + b2[u] + b1[u]
// ---------------------------------------------------------------------------
__global__ __launch_bounds__(256) void projq_kernel(
    const float* __restrict__ query, const float* __restrict__ W2,
    const float* __restrict__ b2, const float* __restrict__ b1,
    float* __restrict__ qb) {
  int b = blockIdx.x;
  int u = blockIdx.y * 256 + threadIdx.x;
  float acc = b2[u] + b1[u];
  const float* q = query + b * DD;
  #pragma unroll 8
  for (int d = 0; d < DD; ++d) acc += q[d] * W2[(size_t)d * UU + u];
  qb[b * UU + u] = acc;
}

// ---------------------------------------------------------------------------
// K2: MFMA score kernel.
// score[row] += sum_u tanh(values[row,:]@W1[:,u] + qb[b,u]) * V[u]
// Tiles: BM=128 (rows), BN=128 (u), BK=32. 256 thr = 4 waves, 64x64/wave.
// A tile = values (fp32->bf16 in staging); B tile = W1t (bf16, n-major).
// LDS pitch 40 bf16 (80B = 20 banks): 8 consecutive rows cover all 32 banks.
// ---------------------------------------------------------------------------
#define BM 128
#define BN 128
#define BK 32
#define LDP 40  // padded pitch in bf16 elements

__global__ __launch_bounds__(256) void score_kernel(
    const float* __restrict__ values, const unsigned short* __restrict__ W1t,
    const float* __restrict__ qb, const float* __restrict__ V,
    float* __restrict__ score) {
  __shared__ unsigned short As[BM][LDP];
  __shared__ unsigned short Bs[BN][LDP];

  const int tid = threadIdx.x;
  const int row0 = blockIdx.y * BM;
  const int n0 = blockIdx.x * BN;
  const int b = row0 >> 11;  // row0 / TT

  const int wid = tid >> 6;           // wave 0..3
  const int lane = tid & 63;
  const int wr = (wid >> 1) * 64;     // wave row base in tile
  const int wc = (wid & 1) * 64;      // wave col base in tile
  const int fr = lane & 15;           // frag row/col within 16
  const int kg = lane >> 4;           // k-group 0..3 (8 bf16 each)

  // staging indices: thread owns 16 contiguous k of one row
  const int sr = tid >> 1;            // 0..127 tile row
  const int sc = (tid & 1) * 16;      // 0 or 16 (k offset)

  const float* aptr = values + (size_t)(row0 + sr) * DD + sc;
  const unsigned short* bptr = W1t + (size_t)(n0 + sr) * DD + sc;

  floatx4 acc[4][4] = {};

  for (int k0 = 0; k0 < DD; k0 += BK) {
    // ---- stage A: fp32 -> bf16 ----
    const float4* ap = (const float4*)(aptr + k0);
    float4 f0 = ap[0], f1 = ap[1], f2 = ap[2], f3 = ap[3];
    ushort8v lo = {f2bf(f0.x), f2bf(f0.y), f2bf(f0.z), f2bf(f0.w),
                   f2bf(f1.x), f2bf(f1.y), f2bf(f1.z), f2bf(f1.w)};
    ushort8v hi = {f2bf(f2.x), f2bf(f2.y), f2bf(f2.z), f2bf(f2.w),
                   f2bf(f3.x), f2bf(f3.y), f2bf(f3.z), f2bf(f3.w)};
    *(ushort8v*)&As[sr][sc] = lo;
    *(ushort8v*)&As[sr][sc + 8] = hi;
    // ---- stage B: already bf16 ----
    const ushort8v* bp = (const ushort8v*)(bptr + k0);
    *(ushort8v*)&Bs[sr][sc] = bp[0];
    *(ushort8v*)&Bs[sr][sc + 8] = bp[1];
    __syncthreads();

    // ---- fragments + MFMA ----
    short8v af[4], bf[4];
    #pragma unroll
    for (int i = 0; i < 4; ++i)
      af[i] = *(const short8v*)&As[wr + i * 16 + fr][kg * 8];
    #pragma unroll
    for (int j = 0; j < 4; ++j)
      bf[j] = *(const short8v*)&Bs[wc + j * 16 + fr][kg * 8];
    #pragma unroll
    for (int i = 0; i < 4; ++i)
      #pragma unroll
      for (int j = 0; j < 4; ++j)
        acc[i][j] = __builtin_amdgcn_mfma_f32_16x16x32_bf16(af[i], bf[j], acc[i][j], 0, 0, 0);
    __syncthreads();
  }

  // ---- epilogue: tanh + V-weighted reduce over u, then over 16 col-lanes ----
  // C/D layout: col = lane&15, row = (lane>>4)*4 + reg  [m89/m91]
  float rowpart[4][4] = {};  // [i][reg]
  #pragma unroll
  for (int j = 0; j < 4; ++j) {
    const int u = n0 + wc + j * 16 + fr;
    const float qv = qb[b * UU + u];
    const float vv = V[u];
    #pragma unroll
    for (int i = 0; i < 4; ++i)
      #pragma unroll
      for (int reg = 0; reg < 4; ++reg)
        rowpart[i][reg] += fast_tanh(acc[i][j][reg] + qv) * vv;
  }
  #pragma unroll
  for (int i = 0; i < 4; ++i)
    #pragma unroll
    for (int reg = 0; reg < 4; ++reg) {
      float p = rowpart[i][reg];
      #pragma unroll
      for (int m = 1; m < 16; m <<= 1) p += __shfl_xor(p, m, 64);
      if (fr == 0)
        atomicAdd(&score[row0 + wr + i * 16 + kg * 4 + reg], p);
    }
}

// ---------------------------------------------------------------------------
// K3: softmax over T per batch. grid (B), block 256.
// ---------------------------------------------------------------------------
__global__ __launch_bounds__(256) void softmax_kernel(
    const float* __restrict__ score, float* __restrict__ attn) {
  const int b = blockIdx.x;
  const int tid = threadIdx.x;
  __shared__ float red[256];

  float m = -INFINITY;
  for (int t = tid; t < TT; t += 256) m = fmaxf(m, score[b * TT + t]);
  red[tid] = m;
  __syncthreads();
  for (int s = 128; s > 0; s >>= 1) {
    if (tid < s) red[tid] = fmaxf(red[tid], red[tid + s]);
    __syncthreads();
  }
  const float bm = red[0];
  __syncthreads();

  float sum = 0.f;
  for (int t = tid; t < TT; t += 256) sum += __expf(score[b * TT + t] - bm);
  red[tid] = sum;
  __syncthreads();
  for (int s = 128; s > 0; s >>= 1) {
    if (tid < s) red[tid] += red[tid + s];
    __syncthreads();
  }
  const float inv = 1.f / red[0];
  __syncthreads();

  for (int t = tid; t < TT; t += 256)
    attn[b * TT + t] = __expf(score[b * TT + t] - bm) * inv;
}

// ---------------------------------------------------------------------------
// K4: context[b,d] = sum_t attn[b,t] * values[b,t,d]  (float4 version)
// grid (SPLIT, B), block 256: 128 threads cover 512 d's as float4; 2 row groups
// ---------------------------------------------------------------------------
#define SPLIT 16
__global__ __launch_bounds__(256) void context_kernel(
    const float* __restrict__ values, const float* __restrict__ attn,
    float* __restrict__ ctx) {
  const int b = blockIdx.y;
  const int t0 = blockIdx.x * (TT / SPLIT);
  const int d = (threadIdx.x & 127) * 4;
  const int rg = threadIdx.x >> 7;  // 0/1
  float4 a = {0.f, 0.f, 0.f, 0.f};
  for (int t = t0 + rg; t < t0 + TT / SPLIT; t += 2) {
    const float w = attn[b * TT + t];
    const float4 v = *(const float4*)(values + (size_t)(b * TT + t) * DD + d);
    a.x += w * v.x; a.y += w * v.y; a.z += w * v.z; a.w += w * v.w;
  }
  atomicAdd(&ctx[b * DD + d + 0], a.x);
  atomicAdd(&ctx[b * DD + d + 1], a.y);
  atomicAdd(&ctx[b * DD + d + 2], a.z);
  atomicAdd(&ctx[b * DD + d + 3], a.w);
}

// ---------------------------------------------------------------------------
extern "C" void kernel_launch(void* const* d_in, const int* in_sizes, int n_in,
                              void* d_out, int out_size, void* d_ws, size_t ws_size,
                              hipStream_t stream) {
  const float* query  = (const float*)d_in[0];
  const float* values = (const float*)d_in[1];
  const float* W1     = (const float*)d_in[2];
  const float* b1     = (const float*)d_in[3];
  const float* W2     = (const float*)d_in[4];
  const float* b2     = (const float*)d_in[5];
  const float* V      = (const float*)d_in[6];
  // d_in[7] = bV: uniform score shift -> softmax-invariant, dropped.

  float* ctx  = (float*)d_out;             // [B,D]
  float* attn = (float*)d_out + BB * DD;   // [B,T,1]

  float* qb          = (float*)d_ws;                    // [B,U] fp32
  float* score       = qb + BB * UU;                    // [B*T] fp32
  unsigned short* w1t = (unsigned short*)(score + BB * TT);  // [U,D] bf16

  hipMemsetAsync(ctx, 0, BB * DD * sizeof(float), stream);
  hipMemsetAsync(score, 0, (size_t)BB * TT * sizeof(float), stream);

  transpose_w1_kernel<<<dim3(16, 16), dim3(32, 8), 0, stream>>>(W1, w1t);
  projq_kernel<<<dim3(BB, UU / 256), 256, 0, stream>>>(query, W2, b2, b1, qb);

  score_kernel<<<dim3(UU / BN, (BB * TT) / BM), 256, 0, stream>>>(
      values, w1t, qb, V, score);

  softmax_kernel<<<BB, 256, 0, stream>>>(score, attn);

  context_kernel<<<dim3(SPLIT, BB), 256, 0, stream>>>(values, attn, ctx);
}

// Round 3
// 155.794 us; speedup vs baseline: 3.3900x; 1.0131x over previous
//
#include <hip/hip_runtime.h>
#include <hip/hip_bf16.h>
#include <math.h>

// BahdanauAttention: B=32, T=2048, D=512, U=512, fp32 in/out.
#define BB 32
#define TT 2048
#define DD 512
#define UU 512

typedef __attribute__((ext_vector_type(8))) short short8v;     // MFMA bf16 A/B frag
typedef __attribute__((ext_vector_type(4))) float floatx4;     // MFMA C/D frag
typedef __attribute__((ext_vector_type(8))) unsigned short ushort8v;

static __device__ inline unsigned short f2bf(float f) {
  __hip_bfloat16 h = __float2bfloat16(f);
  return *reinterpret_cast<unsigned short*>(&h);
}

static __device__ inline float fast_tanh(float x) {
  x = fminf(fmaxf(x, -15.f), 15.f);
  float e2 = __expf(2.f * x);
  return (e2 - 1.f) * __builtin_amdgcn_rcpf(e2 + 1.f);
}

// ---------------------------------------------------------------------------
// K0: transpose W1[k][n] fp32 -> W1t[n][k] bf16 (k-minor: MFMA B-frag layout)
// ---------------------------------------------------------------------------
__global__ __launch_bounds__(256) void transpose_w1_kernel(
    const float* __restrict__ W1, unsigned short* __restrict__ W1t) {
  __shared__ float tile[32][33];
  const int tx = threadIdx.x, ty = threadIdx.y;
  const int bk = blockIdx.y * 32, bn = blockIdx.x * 32;
  #pragma unroll
  for (int i = 0; i < 4; ++i)
    tile[ty + i * 8][tx] = W1[(size_t)(bk + ty + i * 8) * UU + bn + tx];
  __syncthreads();
  #pragma unroll
  for (int i = 0; i < 4; ++i)
    W1t[(size_t)(bn + ty + i * 8) * DD + bk + tx] = f2bf(tile[tx][ty + i * 8]);
}

// ---------------------------------------------------------------------------
// K1: qb[b,u] = query[b,:] @ W2[:,u] + b2[u] + b1[u]
// ---------------------------------------------------------------------------
__global__ __launch_bounds__(256) void projq_kernel(
    const float* __restrict__ query, const float* __restrict__ W2,
    const float* __restrict__ b2, const float* __restrict__ b1,
    float* __restrict__ qb) {
  int b = blockIdx.x;
  int u = blockIdx.y * 256 + threadIdx.x;
  float acc = b2[u] + b1[u];
  const float* q = query + b * DD;
  #pragma unroll 8
  for (int d = 0; d < DD; ++d) acc += q[d] * W2[(size_t)d * UU + u];
  qb[b * UU + u] = acc;
}

// ---------------------------------------------------------------------------
// K2: MFMA score kernel, barrier-free K-loop.
// Block = 64 rows x ALL 512 u. A-panel (64x512 bf16) staged to LDS once;
// each wave owns a 128-u slice; B-frags loaded directly from global W1t
// (L2-resident, 512 KB). No __syncthreads in the K-loop.
// LDS pitch 520 shorts = 1040 B: row stride = 4 banks mod 32 -> 2-way (free).
// ---------------------------------------------------------------------------
#define BM 64
#define LDP 520

__global__ __launch_bounds__(256, 2) void score_kernel(
    const float* __restrict__ values, const unsigned short* __restrict__ W1t,
    const float* __restrict__ qb, const float* __restrict__ V,
    float* __restrict__ score) {
  __shared__ unsigned short As[BM][LDP];

  const int tid = threadIdx.x;
  const int row0 = blockIdx.x * BM;
  const int b = row0 >> 11;            // row0 / TT
  const int lane = tid & 63;
  const int wid = tid >> 6;            // wave 0..3 -> u slice
  const int fr = lane & 15;
  const int kg = lane >> 4;            // 0..3

  // ---- stage A once: 64 rows x 512 k, fp32 -> bf16, fully coalesced ----
  {
    const float* src = values + (size_t)row0 * DD;
    #pragma unroll
    for (int it = 0; it < 16; ++it) {
      const int f = it * 2048 + tid * 8;          // flat float index
      const float4* p = (const float4*)(src + f);
      const float4 x = p[0], y = p[1];
      ushort8v v8 = {f2bf(x.x), f2bf(x.y), f2bf(x.z), f2bf(x.w),
                     f2bf(y.x), f2bf(y.y), f2bf(y.z), f2bf(y.w)};
      *(ushort8v*)&As[f >> 9][f & 511] = v8;
    }
  }
  __syncthreads();

  // ---- barrier-free K-loop: A frags from LDS, B frags straight from L2 ----
  floatx4 acc[4][8] = {};
  const unsigned short* bbase = W1t + (size_t)(wid * 128 + fr) * DD + kg * 8;

  for (int k0 = 0; k0 < DD; k0 += 32) {
    short8v af[4];
    #pragma unroll
    for (int i = 0; i < 4; ++i)
      af[i] = *(const short8v*)&As[i * 16 + fr][k0 + kg * 8];
    #pragma unroll
    for (int j = 0; j < 8; ++j) {
      const short8v bf = *(const short8v*)(bbase + j * (16 * DD) + k0);
      #pragma unroll
      for (int i = 0; i < 4; ++i)
        acc[i][j] = __builtin_amdgcn_mfma_f32_16x16x32_bf16(af[i], bf, acc[i][j], 0, 0, 0);
    }
  }

  // ---- epilogue: tanh + V-weighted reduce over u ----
  // C/D: col(u) = j*16 + fr, row = i*16 + kg*4 + reg
  float rowpart[4][4] = {};
  #pragma unroll
  for (int j = 0; j < 8; ++j) {
    const int u = wid * 128 + j * 16 + fr;
    const float qv = qb[b * UU + u];
    const float vv = V[u];
    #pragma unroll
    for (int i = 0; i < 4; ++i)
      #pragma unroll
      for (int reg = 0; reg < 4; ++reg)
        rowpart[i][reg] += fast_tanh(acc[i][j][reg] + qv) * vv;
  }
  #pragma unroll
  for (int i = 0; i < 4; ++i)
    #pragma unroll
    for (int reg = 0; reg < 4; ++reg) {
      float p = rowpart[i][reg];
      #pragma unroll
      for (int m = 1; m < 16; m <<= 1) p += __shfl_xor(p, m, 64);
      if (fr == 0)  // 4-way atomic (one per wave) per row
        atomicAdd(&score[row0 + i * 16 + kg * 4 + reg], p);
    }
}

// ---------------------------------------------------------------------------
// K3: softmax over T per batch.
// ---------------------------------------------------------------------------
__global__ __launch_bounds__(256) void softmax_kernel(
    const float* __restrict__ score, float* __restrict__ attn) {
  const int b = blockIdx.x;
  const int tid = threadIdx.x;
  __shared__ float red[256];

  float m = -INFINITY;
  for (int t = tid; t < TT; t += 256) m = fmaxf(m, score[b * TT + t]);
  red[tid] = m;
  __syncthreads();
  for (int s = 128; s > 0; s >>= 1) {
    if (tid < s) red[tid] = fmaxf(red[tid], red[tid + s]);
    __syncthreads();
  }
  const float bm = red[0];
  __syncthreads();

  float sum = 0.f;
  for (int t = tid; t < TT; t += 256) sum += __expf(score[b * TT + t] - bm);
  red[tid] = sum;
  __syncthreads();
  for (int s = 128; s > 0; s >>= 1) {
    if (tid < s) red[tid] += red[tid + s];
    __syncthreads();
  }
  const float inv = 1.f / red[0];
  __syncthreads();

  for (int t = tid; t < TT; t += 256)
    attn[b * TT + t] = __expf(score[b * TT + t] - bm) * inv;
}

// ---------------------------------------------------------------------------
// K4: context[b,d] = sum_t attn[b,t] * values[b,t,d]  (float4)
// ---------------------------------------------------------------------------
#define SPLIT 16
__global__ __launch_bounds__(256) void context_kernel(
    const float* __restrict__ values, const float* __restrict__ attn,
    float* __restrict__ ctx) {
  const int b = blockIdx.y;
  const int t0 = blockIdx.x * (TT / SPLIT);
  const int d = (threadIdx.x & 127) * 4;
  const int rg = threadIdx.x >> 7;
  float4 a = {0.f, 0.f, 0.f, 0.f};
  for (int t = t0 + rg; t < t0 + TT / SPLIT; t += 2) {
    const float w = attn[b * TT + t];
    const float4 v = *(const float4*)(values + (size_t)(b * TT + t) * DD + d);
    a.x += w * v.x; a.y += w * v.y; a.z += w * v.z; a.w += w * v.w;
  }
  atomicAdd(&ctx[b * DD + d + 0], a.x);
  atomicAdd(&ctx[b * DD + d + 1], a.y);
  atomicAdd(&ctx[b * DD + d + 2], a.z);
  atomicAdd(&ctx[b * DD + d + 3], a.w);
}

// ---------------------------------------------------------------------------
extern "C" void kernel_launch(void* const* d_in, const int* in_sizes, int n_in,
                              void* d_out, int out_size, void* d_ws, size_t ws_size,
                              hipStream_t stream) {
  const float* query  = (const float*)d_in[0];
  const float* values = (const float*)d_in[1];
  const float* W1     = (const float*)d_in[2];
  const float* b1     = (const float*)d_in[3];
  const float* W2     = (const float*)d_in[4];
  const float* b2     = (const float*)d_in[5];
  const float* V      = (const float*)d_in[6];
  // d_in[7] = bV: uniform score shift -> softmax-invariant, dropped.

  float* ctx  = (float*)d_out;             // [B,D]
  float* attn = (float*)d_out + BB * DD;   // [B,T,1]

  float* qb           = (float*)d_ws;                        // [B,U] fp32
  float* score        = qb + BB * UU;                        // [B*T] fp32
  unsigned short* w1t = (unsigned short*)(score + BB * TT);  // [U,D] bf16

  hipMemsetAsync(ctx, 0, BB * DD * sizeof(float), stream);
  hipMemsetAsync(score, 0, (size_t)BB * TT * sizeof(float), stream);

  transpose_w1_kernel<<<dim3(16, 16), dim3(32, 8), 0, stream>>>(W1, w1t);
  projq_kernel<<<dim3(BB, UU / 256), 256, 0, stream>>>(query, W2, b2, b1, qb);

  score_kernel<<<(BB * TT) / BM, 256, 0, stream>>>(values, w1t, qb, V, score);

  softmax_kernel<<<BB, 256, 0, stream>>>(score, attn);

  context_kernel<<<dim3(SPLIT, BB), 256, 0, stream>>>(values, attn, ctx);
}

// Round 5
// 148.834 us; speedup vs baseline: 3.5485x; 1.0468x over previous
//
#include <hip/hip_runtime.h>
#include <hip/hip_bf16.h>
#include <math.h>

// BahdanauAttention: B=32, T=2048, D=512, U=512, fp32 in/out.
#define BB 32
#define TT 2048
#define DD 512
#define UU 512

typedef __attribute__((ext_vector_type(8))) short short8v;     // MFMA bf16 A/B frag
typedef __attribute__((ext_vector_type(4))) float floatx4;     // MFMA C/D frag
typedef __attribute__((ext_vector_type(8))) unsigned short ushort8v;

static __device__ inline unsigned short f2bf(float f) {
  __hip_bfloat16 h = __float2bfloat16(f);
  return *reinterpret_cast<unsigned short*>(&h);
}

static __device__ inline float fast_tanh(float x) {
  x = fminf(fmaxf(x, -15.f), 15.f);
  float e2 = __expf(2.f * x);
  return (e2 - 1.f) * __builtin_amdgcn_rcpf(e2 + 1.f);
}

// Raw 16B global->LDS copy (dest = wave-uniform base + lane*16).
static __device__ inline void gload16(const void* g, void* l) {
  __builtin_amdgcn_global_load_lds(
      (const __attribute__((address_space(1))) unsigned int*)g,
      (__attribute__((address_space(3))) unsigned int*)(l), 16, 0, 0);
}

// ---------------------------------------------------------------------------
// K0: W1[k][n] fp32 -> w1g blocked bf16: [ntile(4)][ktile(16)][kg(4)][col(128)][8]
// Each 8192B chunk (nt,kt) is the byte image of the GEMM's B-LDS buffer:
// Bs[kg][col][e] = bf16(W1[kt*32+kg*8+e][nt*128+col]).
// ---------------------------------------------------------------------------
__global__ __launch_bounds__(256) void pack_w1_kernel(
    const float* __restrict__ W1, unsigned short* __restrict__ w1g) {
  __shared__ float Wf[32][132];
  const int nt = blockIdx.x, kt = blockIdx.y;
  const int tid = threadIdx.x;
  {
    const int k = tid >> 3;
    const int n16 = (tid & 7) * 16;
    const float* src = W1 + (size_t)(kt * 32 + k) * UU + nt * 128 + n16;
    #pragma unroll
    for (int q = 0; q < 4; ++q) {
      const float4 v = *(const float4*)(src + q * 4);
      Wf[k][n16 + q * 4 + 0] = v.x;
      Wf[k][n16 + q * 4 + 1] = v.y;
      Wf[k][n16 + q * 4 + 2] = v.z;
      Wf[k][n16 + q * 4 + 3] = v.w;
    }
  }
  __syncthreads();
  unsigned short* dst = w1g + ((size_t)nt * 16 + kt) * 4096;  // 8192B chunk
  #pragma unroll
  for (int s = 0; s < 2; ++s) {
    const int idx = s * 256 + tid;   // 16B-chunk index 0..511
    const int kg = idx >> 7;
    const int col = idx & 127;
    ushort8v o;
    #pragma unroll
    for (int e = 0; e < 8; ++e) o[e] = f2bf(Wf[kg * 8 + e][col]);
    *(ushort8v*)(dst + idx * 8) = o;
  }
}

// ---------------------------------------------------------------------------
// K1: qb[b,u] = query[b,:] @ W2[:,u] + b2[u] + b1[u]
// ---------------------------------------------------------------------------
__global__ __launch_bounds__(256) void projq_kernel(
    const float* __restrict__ query, const float* __restrict__ W2,
    const float* __restrict__ b2, const float* __restrict__ b1,
    float* __restrict__ qb) {
  int b = blockIdx.x;
  int u = blockIdx.y * 256 + threadIdx.x;
  float acc = b2[u] + b1[u];
  const float* q = query + b * DD;
  #pragma unroll 8
  for (int d = 0; d < DD; ++d) acc += q[d] * W2[(size_t)d * UU + u];
  qb[b * UU + u] = acc;
}

// ---------------------------------------------------------------------------
// K2: MFMA score kernel, m97-class.
// 128x128 tile, BK=32, 4 waves (2x2, 64x64 each), 16 K-steps.
// A (values): reg-staged fp32->bf16 into blocked LDS [kg][row][8]
//   (each thread: 1 row, 16 k's = 2 kg-groups -> TWO ushort8v writes).
// B (w1g): global_load_lds raw 8KB chunk copy, coalesced.
// ---------------------------------------------------------------------------
#define BM 128
#define BN 128

__global__ __launch_bounds__(256) void score_kernel(
    const float* __restrict__ values, const unsigned short* __restrict__ w1g,
    const float* __restrict__ qb, const float* __restrict__ V,
    float* __restrict__ score) {
  __shared__ __align__(16) unsigned short As[4][BM][8];  // 8KB [kg][row][8]
  __shared__ __align__(16) unsigned short Bs[4][BN][8];  // 8KB [kg][col][8]

  const int tid = threadIdx.x;
  const int row0 = blockIdx.x * BM;
  const int n0 = blockIdx.y * BN;
  const int b = row0 >> 11;           // row0 / TT
  const int lane = tid & 63;
  const int wid = tid >> 6;
  const int wr = (wid >> 1) * 64;
  const int wc = (wid & 1) * 64;
  const int fr = lane & 15;
  const int kg = lane >> 4;

  // A staging coords: thread owns row sr, 16 k's starting at sc (2 kg groups)
  const int sr = tid >> 1;
  const int sc = (tid & 1) * 16;
  const int kg0 = sc >> 3;            // 0 or 2
  const float* abase = values + (size_t)(row0 + sr) * DD + sc;

  const char* bchunk0 = (const char*)(w1g + (size_t)blockIdx.y * 16 * 4096);
  char* bs_flat = (char*)&Bs[0][0][0];

  floatx4 acc[4][4] = {};

  for (int kt = 0; kt < 16; ++kt) {
    // ---- stage B: 8KB via global_load_lds (dense, coalesced) ----
    const char* bsrc = bchunk0 + kt * 8192;
    gload16(bsrc + tid * 16, bs_flat + tid * 16);
    gload16(bsrc + 4096 + tid * 16, bs_flat + 4096 + tid * 16);
    // ---- stage A: 16 floats -> 2x ushort8v (kg0, kg0+1) ----
    {
      const float4* ap = (const float4*)(abase + kt * 32);
      const float4 f0 = ap[0], f1 = ap[1], f2 = ap[2], f3 = ap[3];
      ushort8v lo = {f2bf(f0.x), f2bf(f0.y), f2bf(f0.z), f2bf(f0.w),
                     f2bf(f1.x), f2bf(f1.y), f2bf(f1.z), f2bf(f1.w)};
      ushort8v hi = {f2bf(f2.x), f2bf(f2.y), f2bf(f2.z), f2bf(f2.w),
                     f2bf(f3.x), f2bf(f3.y), f2bf(f3.z), f2bf(f3.w)};
      *(ushort8v*)&As[kg0][sr][0] = lo;
      *(ushort8v*)&As[kg0 + 1][sr][0] = hi;
    }
    __syncthreads();

    // ---- fragments + MFMA ----
    short8v af[4], bf[4];
    #pragma unroll
    for (int i = 0; i < 4; ++i)
      af[i] = *(const short8v*)&As[kg][wr + i * 16 + fr][0];
    #pragma unroll
    for (int j = 0; j < 4; ++j)
      bf[j] = *(const short8v*)&Bs[kg][wc + j * 16 + fr][0];
    #pragma unroll
    for (int i = 0; i < 4; ++i)
      #pragma unroll
      for (int j = 0; j < 4; ++j)
        acc[i][j] = __builtin_amdgcn_mfma_f32_16x16x32_bf16(af[i], bf[j], acc[i][j], 0, 0, 0);
    __syncthreads();
  }

  // ---- epilogue: tanh + V-weighted reduce over u, then 16 col-lanes ----
  // C/D: col(u) = j*16 + fr, row = i*16 + kg*4 + reg   [verified r2]
  float rowpart[4][4] = {};
  #pragma unroll
  for (int j = 0; j < 4; ++j) {
    const int u = n0 + wc + j * 16 + fr;
    const float qv = qb[b * UU + u];
    const float vv = V[u];
    #pragma unroll
    for (int i = 0; i < 4; ++i)
      #pragma unroll
      for (int reg = 0; reg < 4; ++reg)
        rowpart[i][reg] += fast_tanh(acc[i][j][reg] + qv) * vv;
  }
  #pragma unroll
  for (int i = 0; i < 4; ++i)
    #pragma unroll
    for (int reg = 0; reg < 4; ++reg) {
      float p = rowpart[i][reg];
      #pragma unroll
      for (int m = 1; m < 16; m <<= 1) p += __shfl_xor(p, m, 64);
      if (fr == 0)
        atomicAdd(&score[row0 + wr + i * 16 + kg * 4 + reg], p);
    }
}

// ---------------------------------------------------------------------------
// K3: softmax over T per batch.
// ---------------------------------------------------------------------------
__global__ __launch_bounds__(256) void softmax_kernel(
    const float* __restrict__ score, float* __restrict__ attn) {
  const int b = blockIdx.x;
  const int tid = threadIdx.x;
  __shared__ float red[256];

  float m = -INFINITY;
  for (int t = tid; t < TT; t += 256) m = fmaxf(m, score[b * TT + t]);
  red[tid] = m;
  __syncthreads();
  for (int s = 128; s > 0; s >>= 1) {
    if (tid < s) red[tid] = fmaxf(red[tid], red[tid + s]);
    __syncthreads();
  }
  const float bm = red[0];
  __syncthreads();

  float sum = 0.f;
  for (int t = tid; t < TT; t += 256) sum += __expf(score[b * TT + t] - bm);
  red[tid] = sum;
  __syncthreads();
  for (int s = 128; s > 0; s >>= 1) {
    if (tid < s) red[tid] += red[tid + s];
    __syncthreads();
  }
  const float inv = 1.f / red[0];
  __syncthreads();

  for (int t = tid; t < TT; t += 256)
    attn[b * TT + t] = __expf(score[b * TT + t] - bm) * inv;
}

// ---------------------------------------------------------------------------
// K4: context[b,d] = sum_t attn[b,t] * values[b,t,d]  (float4)
// ---------------------------------------------------------------------------
#define SPLIT 16
__global__ __launch_bounds__(256) void context_kernel(
    const float* __restrict__ values, const float* __restrict__ attn,
    float* __restrict__ ctx) {
  const int b = blockIdx.y;
  const int t0 = blockIdx.x * (TT / SPLIT);
  const int d = (threadIdx.x & 127) * 4;
  const int rg = threadIdx.x >> 7;
  float4 a = {0.f, 0.f, 0.f, 0.f};
  for (int t = t0 + rg; t < t0 + TT / SPLIT; t += 2) {
    const float w = attn[b * TT + t];
    const float4 v = *(const float4*)(values + (size_t)(b * TT + t) * DD + d);
    a.x += w * v.x; a.y += w * v.y; a.z += w * v.z; a.w += w * v.w;
  }
  atomicAdd(&ctx[b * DD + d + 0], a.x);
  atomicAdd(&ctx[b * DD + d + 1], a.y);
  atomicAdd(&ctx[b * DD + d + 2], a.z);
  atomicAdd(&ctx[b * DD + d + 3], a.w);
}

// ---------------------------------------------------------------------------
extern "C" void kernel_launch(void* const* d_in, const int* in_sizes, int n_in,
                              void* d_out, int out_size, void* d_ws, size_t ws_size,
                              hipStream_t stream) {
  const float* query  = (const float*)d_in[0];
  const float* values = (const float*)d_in[1];
  const float* W1     = (const float*)d_in[2];
  const float* b1     = (const float*)d_in[3];
  const float* W2     = (const float*)d_in[4];
  const float* b2     = (const float*)d_in[5];
  const float* V      = (const float*)d_in[6];
  // d_in[7] = bV: uniform score shift -> softmax-invariant, dropped.

  float* ctx  = (float*)d_out;             // [B,D]
  float* attn = (float*)d_out + BB * DD;   // [B,T,1]

  float* qb           = (float*)d_ws;                        // [B,U] fp32
  float* score        = qb + BB * UU;                        // [B*T] fp32
  unsigned short* w1g = (unsigned short*)(score + BB * TT);  // 512KB blocked bf16

  hipMemsetAsync(ctx, 0, BB * DD * sizeof(float), stream);
  hipMemsetAsync(score, 0, (size_t)BB * TT * sizeof(float), stream);

  pack_w1_kernel<<<dim3(4, 16), 256, 0, stream>>>(W1, w1g);
  projq_kernel<<<dim3(BB, UU / 256), 256, 0, stream>>>(query, W2, b2, b1, qb);

  score_kernel<<<dim3((BB * TT) / BM, UU / BN), 256, 0, stream>>>(
      values, w1g, qb, V, score);

  softmax_kernel<<<BB, 256, 0, stream>>>(score, attn);

  context_kernel<<<dim3(SPLIT, BB), 256, 0, stream>>>(values, attn, ctx);
}